// Round 13
// baseline (143.039 us; speedup 1.0000x reference)
//
#include <hip/hip_runtime.h>
#include <stdint.h>

using u16 = unsigned short;
using u32 = unsigned int;
using bf16x8 = __attribute__((ext_vector_type(8))) __bf16;
using f32x4  = __attribute__((ext_vector_type(4))) float;

// B=8, N=1024, C=1024, H=16, D=64
#define NB 8
#define NN 1024
#define NC 1024
#define NH 16
#define ND 64
// SCALE * log2(e) folded into Wq/bq so attention uses exp2 directly
#define QSCALE 0.18033688011112042f

__device__ __forceinline__ u16 f2bf(float f) {
  u32 u = __float_as_uint(f);
  return (u16)((u + 0x7fffu + ((u >> 16) & 1u)) >> 16);  // RNE
}
__device__ __forceinline__ u16 bfc(float f) {
  __bf16 b = (__bf16)f;
  return __builtin_bit_cast(u16, b);
}
__device__ __forceinline__ u32 pack2(u16 a, u16 b) { return (u32)a | ((u32)b << 16); }

__device__ __forceinline__ void gload16(const void* g, void* l) {
  __builtin_amdgcn_global_load_lds((__attribute__((address_space(1))) const u32*)g,
                                   (__attribute__((address_space(3))) u32*)l, 16, 0, 0);
}

// ---------------- merged prep: x->bf16 | weights->Wt ----------------
// grid: [0,8192) cvt_x (2M float4), [8192,8960) prep_w (16 k-blk x 48 c-blk)
__global__ void k_prep(const float* __restrict__ x, const float* __restrict__ Wq,
                       const float* __restrict__ Wkv,
                       u16* __restrict__ xb, u16* __restrict__ Wt) {
  __shared__ u16 tile[64][72];
  int bid = blockIdx.x;
  int t = threadIdx.x;
  if (bid < 8192) {                    // ---- x fp32 -> bf16 ----
    int i = bid * 256 + t;
    float4 v = ((const float4*)x)[i];
    ((uint2*)xb)[i] = make_uint2(pack2(f2bf(v.x), f2bf(v.y)), pack2(f2bf(v.z), f2bf(v.w)));
    return;
  }
  {                                    // ---- weights -> Wt[3072][1024] (n-major) ----
    int pb = bid - 8192;
    int k0 = (pb & 15) << 6;
    int c0 = (pb >> 4) << 6;
    bool isQ = (c0 < 1024);
    const float* src = isQ ? Wq : Wkv;
    int ldw  = isQ ? 1024 : 2048;
    int csrc = isQ ? c0 : (c0 - 1024);
    float sc = isQ ? QSCALE : 1.0f;

    int r  = t >> 2;
    int cq = (t & 3) << 4;
    const float* p = src + (size_t)(k0 + r) * ldw + csrc + cq;
#pragma unroll
    for (int j = 0; j < 16; j += 4) {
      float4 v = *(const float4*)(p + j);
      tile[r][cq + j + 0] = f2bf(v.x * sc);
      tile[r][cq + j + 1] = f2bf(v.y * sc);
      tile[r][cq + j + 2] = f2bf(v.z * sc);
      tile[r][cq + j + 3] = f2bf(v.w * sc);
    }
    __syncthreads();
    int co = t >> 2;
    int kq = (t & 3) << 4;
    u16 v0[16];
#pragma unroll
    for (int j = 0; j < 16; ++j) v0[j] = tile[kq + j][co];
    uint4 o0, o1;
    o0.x = pack2(v0[0], v0[1]);  o0.y = pack2(v0[2], v0[3]);
    o0.z = pack2(v0[4], v0[5]);  o0.w = pack2(v0[6], v0[7]);
    o1.x = pack2(v0[8], v0[9]);  o1.y = pack2(v0[10], v0[11]);
    o1.z = pack2(v0[12], v0[13]); o1.w = pack2(v0[14], v0[15]);
    u16* dst = Wt + (size_t)(c0 + co) * 1024 + k0 + kq;
    *(uint4*)dst = o0;
    *(uint4*)(dst + 8) = o1;
  }
}

// ---------------- fused QKV projection GEMM: minimal-sync big-tile ----------------
// BM=256 BN=384 BK=64, grid 256 = EXACTLY 1 round at 1 blk/CU. LDS 160KiB dbuf.
// ONE vmcnt(0) + ONE barrier per K-tile (no intra-tile hazard with 1-tile stage
// lead into the non-read buffer). Interior is compiler-scheduled free-form
// (compiler emits fine lgkmcnt itself; all phase/sched_barrier pinning removed —
// r8-r12 showed per-phase sync was the dominant cost, not pipes).
// 8 waves (2Mx4N), per-wave 128x96, acc[8][6]. T2 chunk-swizzle; m-panel XCD map.
__launch_bounds__(512, 2)
__global__ void k_gemm(const u16* __restrict__ A, const u16* __restrict__ Bw,
                       const float* __restrict__ bq, const float* __restrict__ bkv,
                       u16* __restrict__ qws, u16* __restrict__ kws, u16* __restrict__ vtw) {
  __shared__ __align__(16) u16 LA[2][16384];   // [buf][256 rows x 64 k]
  __shared__ __align__(16) u16 LB[2][24576];   // [buf][384 rows x 64 k]
  int flat = blockIdx.x;                       // 256 = 8 xcd * (4m x 8n)
  int xcd = flat & 7, idx = flat >> 3;         // per XCD: 4 m-tiles x 8 n-tiles
  int m0 = (xcd * 4 + (idx & 3)) * 256;        // A panel 2MB L2-resident per XCD
  int n0 = (idx >> 2) * 384;
  int tid = threadIdx.x;
  int w = tid >> 6, lane = tid & 63;
  int lo = lane & 15, hi = lane >> 4;
  int wm = w >> 2, wn = w & 3;                 // wave grid 2(M) x 4(N)

  f32x4 acc[8][6] = {};   // rows: m0 + wm*128 + q*64 + mi*16 + hi*4+r; cols: n0 + wn*96 + ni*16 + lo

  // staging: pass = 64 rows; A 4 passes, B 6 passes; linear LDS dest,
  // inverse-swizzled global chunk: (tid&7) ^ ((row)&7), row-in-pass = tid>>3
  int cs = ((tid & 7) ^ ((tid >> 3) & 7)) * 8;
  const u16* Ag = A  + (size_t)(m0 + (tid >> 3)) * 1024 + cs;
  const u16* Bg = Bw + (size_t)(n0 + (tid >> 3)) * 1024 + cs;

  // read side: chunk = (ks*4 + hi) ^ (row&7), row&7 == lo&7 for all fragments
  int ck0 = ((hi ^ (lo & 7)) << 3);
  int ck1 = (((4 + hi) ^ (lo & 7)) << 3);
  const u16* laR = &LA[0][(wm * 128 + lo) * 64];
  const u16* lbR = &LB[0][(wn * 96 + lo) * 64];

#define MFMA_(a, b, c) __builtin_amdgcn_mfma_f32_16x16x32_bf16(a, b, c, 0, 0, 0)
#define ST_A(BUF, P, KT) gload16(Ag + (size_t)((P) * 64) * 1024 + (KT) * 64, &LA[BUF][(P) * 4096 + tid * 8]);
#define ST_B(BUF, P, KT) gload16(Bg + (size_t)((P) * 64) * 1024 + (KT) * 64, &LB[BUF][(P) * 4096 + tid * 8]);
#define ST_TILE(BUF, KT)                                                     \
  ST_A(BUF, 0, KT); ST_A(BUF, 1, KT); ST_A(BUF, 2, KT); ST_A(BUF, 3, KT);    \
  ST_B(BUF, 0, KT); ST_B(BUF, 1, KT); ST_B(BUF, 2, KT);                      \
  ST_B(BUF, 3, KT); ST_B(BUF, 4, KT); ST_B(BUF, 5, KT);

  // ---- prologue: stage tile 0 into buf 0, drain, barrier ----
  ST_TILE(0, 0);
  asm volatile("s_waitcnt vmcnt(0)" ::: "memory");
  __builtin_amdgcn_s_barrier();

#pragma unroll 1
  for (int t = 0; t < 16; ++t) {
    int b = t & 1;
    const u16* la = laR + b * 16384;
    const u16* lb = lbR + b * 24576;

    // ---- stage next tile FIRST (into non-read buffer; full-tile latency cover) ----
    if (t < 15) { ST_TILE(b ^ 1, t + 1); }
    __builtin_amdgcn_sched_barrier(0);   // keep stage issue ahead of compute

    // ---- free-form compute: compiler schedules ds_read/MFMA interleave ----
    bf16x8 bfr[6][2];
#pragma unroll
    for (int ni = 0; ni < 6; ++ni) {
      bfr[ni][0] = *(const bf16x8*)(lb + ni * 1024 + ck0);
      bfr[ni][1] = *(const bf16x8*)(lb + ni * 1024 + ck1);
    }
#pragma unroll
    for (int q = 0; q < 2; ++q) {
      bf16x8 af[4][2];
#pragma unroll
      for (int mi = 0; mi < 4; ++mi) {
        af[mi][0] = *(const bf16x8*)(la + (q * 64 + mi * 16) * 64 + ck0);
        af[mi][1] = *(const bf16x8*)(la + (q * 64 + mi * 16) * 64 + ck1);
      }
#pragma unroll
      for (int ni = 0; ni < 6; ++ni)
#pragma unroll
        for (int mi = 0; mi < 4; ++mi) {
          acc[q * 4 + mi][ni] = MFMA_(af[mi][0], bfr[ni][0], acc[q * 4 + mi][ni]);
          acc[q * 4 + mi][ni] = MFMA_(af[mi][1], bfr[ni][1], acc[q * 4 + mi][ni]);
        }
    }

    // ---- single sync point per tile ----
    if (t < 15) {
      asm volatile("s_waitcnt vmcnt(0) lgkmcnt(0)" ::: "memory");  // staged tile landed; reads drained
      __builtin_amdgcn_s_barrier();
    }
  }
#undef ST_TILE
#undef ST_A
#undef ST_B
#undef MFMA_

  // ---- epilogue: inline bias, bf16, scatter q/k [b,h,n,d]; V direct-transposed [b,h,d,n] ----
#pragma unroll
  for (int ni = 0; ni < 6; ++ni) {
    int c = n0 + wn * 96 + ni * 16 + lo;   // 0..3071; 16-col groups never straddle q/k/v
    float bvl = (c < 1024) ? bq[c] * QSCALE : bkv[c - 1024];
    if (c < 2048) {
#pragma unroll
      for (int mi = 0; mi < 8; ++mi) {
#pragma unroll
        for (int r = 0; r < 4; ++r) {
          int m = m0 + wm * 128 + mi * 16 + hi * 4 + r;
          int b = m >> 10, tok = m & 1023;
          u16 o = f2bf(acc[mi][ni][r] + bvl);
          if (c < 1024) {
            int h = c >> 6, d = c & 63;
            qws[((size_t)(b * 16 + h) * 1024 + tok) * 64 + d] = o;
          } else {
            int c2 = c - 1024; int h = c2 >> 6, d = c2 & 63;
            kws[((size_t)(b * 16 + h) * 1024 + tok) * 64 + d] = o;
          }
        }
      }
    } else {
      int c2 = c - 2048; int h = c2 >> 6, d = c2 & 63;
#pragma unroll
      for (int mi = 0; mi < 8; ++mi) {
        int m = m0 + wm * 128 + mi * 16 + hi * 4;   // 4-aligned, never crosses batch
        int b = m >> 10, tok = m & 1023;
        ushort4 pk;
        pk.x = bfc(acc[mi][ni][0] + bvl);
        pk.y = bfc(acc[mi][ni][1] + bvl);
        pk.z = bfc(acc[mi][ni][2] + bvl);
        pk.w = bfc(acc[mi][ni][3] + bvl);
        *(ushort4*)&vtw[((size_t)(b * 16 + h) * 64 + d) * 1024 + tok] = pk;
      }
    }
  }
}

// ---------------- flash attention: 2 q-sets per block ----------------
// grid (bh=128, qb=4): each block processes q0 and q0+128 against the SAME
// staged K/V tiles; K/V fragments read from LDS once, used for both q-sets.
// Swapped QK^T + in-lane softmax + defer-max (THR=8, log2 domain); T5 setprio.
__launch_bounds__(512)
__global__ void k_attn(const u16* __restrict__ q, const u16* __restrict__ k,
                       const u16* __restrict__ vt, float* __restrict__ out) {
  __shared__ __align__(16) u16 Ks[2][4096];    // [buf][row*64+col], chunk-swizzled
  __shared__ __align__(16) u16 Vs[2][4096];    // [buf][d*64+k], chunk-swizzled
  __shared__ __align__(16) u16 P[2][8][16][72]; // per-qset, per-wave P relayout [q][key]
  int bh = blockIdx.x;
  int q0 = blockIdx.y * 256;
  int tid = threadIdx.x;
  int w = tid >> 6, lane = tid & 63;
  int lo = lane & 15, hi = lane >> 4;
  int b = bh >> 4, h = bh & 15;

  const u16* kbase = k  + (size_t)bh * 65536;
  const u16* vbase = vt + (size_t)bh * 65536;

  int srow = w * 8 + (lane >> 3);
  int cg   = (lane & 7) ^ ((lane >> 3) & 7);
  const u16* gK = kbase + (size_t)srow * 64   + cg * 8;
  const u16* gV = vbase + (size_t)srow * 1024 + cg * 8;
  u16* lK0 = &Ks[0][w * 512];
  u16* lK1 = &Ks[1][w * 512];
  u16* lV0 = &Vs[0][w * 512];
  u16* lV1 = &Vs[1][w * 512];

  const u16* qp = q + ((size_t)bh * 1024 + q0 + w * 16 + lo) * 64 + hi * 8;
  bf16x8 qfA0 = *(const bf16x8*)(qp);
  bf16x8 qfA1 = *(const bf16x8*)(qp + 32);
  bf16x8 qfB0 = *(const bf16x8*)(qp + 128 * 64);
  bf16x8 qfB1 = *(const bf16x8*)(qp + 128 * 64 + 32);

  f32x4 accA[4] = {}, accB[4] = {};
  float mA = -1e30f, lA = 0.f;
  float mB = -1e30f, lB = 0.f;

  int sw = lo & 7;

  gload16(gK, lK0);
  gload16(gV, lV0);
  __syncthreads();

  for (int t = 0; t < 16; ++t) {
    int cur = t & 1;
    if (t < 15) {
      gload16(gK + (t + 1) * 4096, cur ? lK0 : lK1);
      gload16(gV + (t + 1) * 64,   cur ? lV0 : lV1);
    }
    // ---- S^T for both q-sets; K frags read ONCE ----
    f32x4 sA[4] = {}, sB[4] = {};
    const u16* kb = Ks[cur];
    __builtin_amdgcn_s_setprio(1);
#pragma unroll
    for (int ni = 0; ni < 4; ++ni) {
      const u16* kp = kb + (ni * 16 + lo) * 64;
      bf16x8 kf0 = *(const bf16x8*)(kp + ((hi ^ sw) * 8));
      bf16x8 kf1 = *(const bf16x8*)(kp + (((4 + hi) ^ sw) * 8));
      sA[ni] = __builtin_amdgcn_mfma_f32_16x16x32_bf16(kf0, qfA0, sA[ni], 0, 0, 0);
      sA[ni] = __builtin_amdgcn_mfma_f32_16x16x32_bf16(kf1, qfA1, sA[ni], 0, 0, 0);
      sB[ni] = __builtin_amdgcn_mfma_f32_16x16x32_bf16(kf0, qfB0, sB[ni], 0, 0, 0);
      sB[ni] = __builtin_amdgcn_mfma_f32_16x16x32_bf16(kf1, qfB1, sB[ni], 0, 0, 0);
    }
    __builtin_amdgcn_s_setprio(0);

    // ---- softmax A and B (independent VALU chains) ----
#define SOFTMAX(S, M, L, PI)                                                   \
    {                                                                          \
      float a0 = fmaxf(fmaxf(S[0][0], S[0][1]), fmaxf(S[0][2], S[0][3]));      \
      float a1 = fmaxf(fmaxf(S[1][0], S[1][1]), fmaxf(S[1][2], S[1][3]));      \
      float a2 = fmaxf(fmaxf(S[2][0], S[2][1]), fmaxf(S[2][2], S[2][3]));      \
      float a3 = fmaxf(fmaxf(S[3][0], S[3][1]), fmaxf(S[3][2], S[3][3]));      \
      float pm = fmaxf(fmaxf(a0, a1), fmaxf(a2, a3));                          \
      pm = fmaxf(pm, __shfl_xor(pm, 16));                                      \
      pm = fmaxf(pm, __shfl_xor(pm, 32));                                      \
      if (!__all(pm <= M + 8.0f)) {                                            \
        float mn = fmaxf(M, pm);                                               \
        float corr = __builtin_amdgcn_exp2f(M - mn);                           \
        M = mn;                                                                \
        L *= corr;                                                             \
        float cr[4];                                                           \
        _Pragma("unroll")                                                      \
        for (int r = 0; r < 4; ++r) cr[r] = __shfl(corr, hi * 4 + r);          \
        _Pragma("unroll")                                                      \
        for (int ci = 0; ci < 4; ++ci)                                         \
          _Pragma("unroll")                                                    \
          for (int r = 0; r < 4; ++r) acc##PI[ci][r] *= cr[r];                 \
      }                                                                        \
      float rs = 0.f;                                                          \
      _Pragma("unroll")                                                        \
      for (int ni = 0; ni < 4; ++ni) {                                         \
        float p0 = __builtin_amdgcn_exp2f(S[ni][0] - M);                       \
        float p1 = __builtin_amdgcn_exp2f(S[ni][1] - M);                       \
        float p2 = __builtin_amdgcn_exp2f(S[ni][2] - M);                       \
        float p3 = __builtin_amdgcn_exp2f(S[ni][3] - M);                       \
        rs += (p0 + p1) + (p2 + p3);                                           \
        ushort4 pk;                                                            \
        pk.x = bfc(p0); pk.y = bfc(p1); pk.z = bfc(p2); pk.w = bfc(p3);        \
        *(ushort4*)&P[PI##I][w][lo][ni * 16 + hi * 4] = pk;                    \
      }                                                                        \
      rs += __shfl_xor(rs, 16);                                                \
      rs += __shfl_xor(rs, 32);                                                \
      L += rs;                                                                 \
    }
#define AI 0
#define BI 1
    SOFTMAX(sA, mA, lA, A)
    SOFTMAX(sB, mB, lB, B)
#undef SOFTMAX

    // ---- PV for both q-sets; V frags read ONCE ----
    bf16x8 pA0 = *(const bf16x8*)(&P[0][w][lo][hi * 8]);
    bf16x8 pA1 = *(const bf16x8*)(&P[0][w][lo][32 + hi * 8]);
    bf16x8 pB0 = *(const bf16x8*)(&P[1][w][lo][hi * 8]);
    bf16x8 pB1 = *(const bf16x8*)(&P[1][w][lo][32 + hi * 8]);
    const u16* vb = Vs[cur];
    __builtin_amdgcn_s_setprio(1);
#pragma unroll
    for (int ci = 0; ci < 4; ++ci) {
      const u16* vp = vb + (ci * 16 + lo) * 64;
      bf16x8 vf0 = *(const bf16x8*)(vp + ((hi ^ sw) * 8));
      bf16x8 vf1 = *(const bf16x8*)(vp + (((4 + hi) ^ sw) * 8));
      accA[ci] = __builtin_amdgcn_mfma_f32_16x16x32_bf16(pA0, vf0, accA[ci], 0, 0, 0);
      accA[ci] = __builtin_amdgcn_mfma_f32_16x16x32_bf16(pA1, vf1, accA[ci], 0, 0, 0);
      accB[ci] = __builtin_amdgcn_mfma_f32_16x16x32_bf16(pB0, vf0, accB[ci], 0, 0, 0);
      accB[ci] = __builtin_amdgcn_mfma_f32_16x16x32_bf16(pB1, vf1, accB[ci], 0, 0, 0);
    }
    __builtin_amdgcn_s_setprio(0);
    __syncthreads();
  }
  // ---- normalize + store both q-sets ----
  {
    float inv = 1.0f / lA;
    float ivr[4];
#pragma unroll
    for (int r = 0; r < 4; ++r) ivr[r] = __shfl(inv, hi * 4 + r);
#pragma unroll
    for (int r = 0; r < 4; ++r) {
      int n = q0 + w * 16 + hi * 4 + r;
      float* dst = out + ((size_t)(b * 1024 + n)) * 1024 + h * 64;
#pragma unroll
      for (int ci = 0; ci < 4; ++ci) dst[ci * 16 + lo] = accA[ci][r] * ivr[r];
    }
  }
  {
    float inv = 1.0f / lB;
    float ivr[4];
#pragma unroll
    for (int r = 0; r < 4; ++r) ivr[r] = __shfl(inv, hi * 4 + r);
#pragma unroll
    for (int r = 0; r < 4; ++r) {
      int n = q0 + 128 + w * 16 + hi * 4 + r;
      float* dst = out + ((size_t)(b * 1024 + n)) * 1024 + h * 64;
#pragma unroll
      for (int ci = 0; ci < 4; ++ci) dst[ci * 16 + lo] = accB[ci][r] * ivr[r];
    }
  }
}

extern "C" void kernel_launch(void* const* d_in, const int* in_sizes, int n_in,
                              void* d_out, int out_size, void* d_ws, size_t ws_size,
                              hipStream_t stream) {
  const float* x   = (const float*)d_in[0];
  const float* Wq  = (const float*)d_in[1];
  const float* bq  = (const float*)d_in[2];
  const float* Wkv = (const float*)d_in[3];
  const float* bkv = (const float*)d_in[4];
  float* out = (float*)d_out;

  char* ws = (char*)d_ws;
  u16*   xb   = (u16*)(ws);                       // 16,777,216 B
  u16*   Wt   = (u16*)(ws + 16777216);            //  6,291,456 B
  u16*   qws  = (u16*)(ws + 23080960);            // 16,777,216 B
  u16*   kws  = (u16*)(ws + 39858176);            // 16,777,216 B
  u16*   vtw  = (u16*)(ws + 73412608);            // 16,777,216 B (written transposed by k_gemm)

  k_prep<<<8960, 256, 0, stream>>>(x, Wq, Wkv, xb, Wt);
  k_gemm<<<256, 512, 0, stream>>>(xb, Wt, bq, bkv, qws, kws, vtw);
  {
    dim3 g(128, 4);
    k_attn<<<g, 512, 0, stream>>>(qws, kws, vtw, out);
  }
}

// Round 14
// 131.304 us; speedup vs baseline: 1.0894x; 1.0894x over previous
//
#include <hip/hip_runtime.h>
#include <stdint.h>

using u16 = unsigned short;
using u32 = unsigned int;
using bf16x8 = __attribute__((ext_vector_type(8))) __bf16;
using f32x4  = __attribute__((ext_vector_type(4))) float;

// B=8, N=1024, C=1024, H=16, D=64
#define NB 8
#define NN 1024
#define NC 1024
#define NH 16
#define ND 64
// SCALE * log2(e) folded into Wq/bq so attention uses exp2 directly
#define QSCALE 0.18033688011112042f

__device__ __forceinline__ u16 f2bf(float f) {
  u32 u = __float_as_uint(f);
  return (u16)((u + 0x7fffu + ((u >> 16) & 1u)) >> 16);  // RNE
}
__device__ __forceinline__ u16 bfc(float f) {
  __bf16 b = (__bf16)f;
  return __builtin_bit_cast(u16, b);
}
__device__ __forceinline__ u32 pack2(u16 a, u16 b) { return (u32)a | ((u32)b << 16); }

__device__ __forceinline__ void gload16(const void* g, void* l) {
  __builtin_amdgcn_global_load_lds((__attribute__((address_space(1))) const u32*)g,
                                   (__attribute__((address_space(3))) u32*)l, 16, 0, 0);
}

// ---------------- merged prep: x->bf16 | weights->Wt ----------------
// grid: [0,8192) cvt_x (2M float4), [8192,8960) prep_w (16 k-blk x 48 c-blk)
__global__ void k_prep(const float* __restrict__ x, const float* __restrict__ Wq,
                       const float* __restrict__ Wkv,
                       u16* __restrict__ xb, u16* __restrict__ Wt) {
  __shared__ u16 tile[64][72];
  int bid = blockIdx.x;
  int t = threadIdx.x;
  if (bid < 8192) {                    // ---- x fp32 -> bf16 ----
    int i = bid * 256 + t;
    float4 v = ((const float4*)x)[i];
    ((uint2*)xb)[i] = make_uint2(pack2(f2bf(v.x), f2bf(v.y)), pack2(f2bf(v.z), f2bf(v.w)));
    return;
  }
  {                                    // ---- weights -> Wt[3072][1024] (n-major) ----
    int pb = bid - 8192;
    int k0 = (pb & 15) << 6;
    int c0 = (pb >> 4) << 6;
    bool isQ = (c0 < 1024);
    const float* src = isQ ? Wq : Wkv;
    int ldw  = isQ ? 1024 : 2048;
    int csrc = isQ ? c0 : (c0 - 1024);
    float sc = isQ ? QSCALE : 1.0f;

    int r  = t >> 2;
    int cq = (t & 3) << 4;
    const float* p = src + (size_t)(k0 + r) * ldw + csrc + cq;
#pragma unroll
    for (int j = 0; j < 16; j += 4) {
      float4 v = *(const float4*)(p + j);
      tile[r][cq + j + 0] = f2bf(v.x * sc);
      tile[r][cq + j + 1] = f2bf(v.y * sc);
      tile[r][cq + j + 2] = f2bf(v.z * sc);
      tile[r][cq + j + 3] = f2bf(v.w * sc);
    }
    __syncthreads();
    int co = t >> 2;
    int kq = (t & 3) << 4;
    u16 v0[16];
#pragma unroll
    for (int j = 0; j < 16; ++j) v0[j] = tile[kq + j][co];
    uint4 o0, o1;
    o0.x = pack2(v0[0], v0[1]);  o0.y = pack2(v0[2], v0[3]);
    o0.z = pack2(v0[4], v0[5]);  o0.w = pack2(v0[6], v0[7]);
    o1.x = pack2(v0[8], v0[9]);  o1.y = pack2(v0[10], v0[11]);
    o1.z = pack2(v0[12], v0[13]); o1.w = pack2(v0[14], v0[15]);
    u16* dst = Wt + (size_t)(c0 + co) * 1024 + k0 + kq;
    *(uint4*)dst = o0;
    *(uint4*)(dst + 8) = o1;
  }
}

// ---------------- fused QKV projection GEMM: 256x384, EXACT 1-round packing ----------------
// BM=256 BN=384 BK=64, grid 256 = 32m x 8n tiles = EXACTLY 1 round at 1 blk/CU.
// LDS = 2x(32KB A + 48KB B) = 163840 B (full 160KiB). 8 waves (2Mx4N), per-wave
// 128x96, acc[8][6] (AGPR). 12 phases/tile (2 Q x 6 NI, 8 MFMA each).
// Staging: 1-tile lead into the non-read buffer (WAR-free), 10 passes spread
// over phases, vmcnt(0) at tile end with ~full-tile cover. T2 chunk-swizzle;
// m-panel XCD map (FETCH-verified r10). PLATEAU: 10 schedule variants (r3-r13)
// all land 74-91us; this is the best (74us, MfmaUtil 27%). Closed.
__launch_bounds__(512, 2)
__global__ void k_gemm(const u16* __restrict__ A, const u16* __restrict__ Bw,
                       const float* __restrict__ bq, const float* __restrict__ bkv,
                       u16* __restrict__ qws, u16* __restrict__ kws, u16* __restrict__ vtw) {
  __shared__ __align__(16) u16 LA[2][16384];   // [buf][256 rows x 64 k]
  __shared__ __align__(16) u16 LB[2][24576];   // [buf][384 rows x 64 k]
  int flat = blockIdx.x;                       // 256 = 8 xcd * (4m x 8n)
  int xcd = flat & 7, idx = flat >> 3;         // per XCD: 4 m-tiles x 8 n-tiles
  int m0 = (xcd * 4 + (idx & 3)) * 256;        // A panel 2MB L2-resident per XCD
  int n0 = (idx >> 2) * 384;
  int tid = threadIdx.x;
  int w = tid >> 6, lane = tid & 63;
  int lo = lane & 15, hi = lane >> 4;
  int wm = w >> 2, wn = w & 3;                 // wave grid 2(M) x 4(N)

  f32x4 acc[8][6] = {};   // rows: m0 + wm*128 + q*64 + mi*16 + hi*4+r; cols: n0 + wn*96 + ni*16 + lo

  // staging: pass = 64 rows; A 4 passes, B 6 passes; linear LDS dest,
  // inverse-swizzled global chunk: (tid&7) ^ ((row)&7), row-in-pass = tid>>3
  int cs = ((tid & 7) ^ ((tid >> 3) & 7)) * 8;
  const u16* Ag = A  + (size_t)(m0 + (tid >> 3)) * 1024 + cs;
  const u16* Bg = Bw + (size_t)(n0 + (tid >> 3)) * 1024 + cs;

  // read side: chunk = (ks*4 + hi) ^ (row&7), row&7 == lo&7 for all fragments
  int ck0 = ((hi ^ (lo & 7)) << 3);
  int ck1 = (((4 + hi) ^ (lo & 7)) << 3);
  const u16* laR = &LA[0][(wm * 128 + lo) * 64];
  const u16* lbR = &LB[0][(wn * 96 + lo) * 64];

#define MFMA_(a, b, c) __builtin_amdgcn_mfma_f32_16x16x32_bf16(a, b, c, 0, 0, 0)
#define SBAR() __builtin_amdgcn_sched_barrier(0); __builtin_amdgcn_s_barrier(); __builtin_amdgcn_sched_barrier(0)
#define LGKM0() asm volatile("s_waitcnt lgkmcnt(0)" ::: "memory"); __builtin_amdgcn_sched_barrier(0)

#define ST_A(BUF, P, KT) gload16(Ag + (size_t)((P) * 64) * 1024 + (KT) * 64, &LA[BUF][(P) * 4096 + tid * 8]);
#define ST_B(BUF, P, KT) gload16(Bg + (size_t)((P) * 64) * 1024 + (KT) * 64, &LB[BUF][(P) * 4096 + tid * 8]);

  // ---- prologue: stage tile 0 into buf 0 (10 passes), drain, barrier ----
  ST_A(0, 0, 0); ST_A(0, 1, 0); ST_A(0, 2, 0); ST_A(0, 3, 0);
  ST_B(0, 0, 0); ST_B(0, 1, 0); ST_B(0, 2, 0); ST_B(0, 3, 0); ST_B(0, 4, 0); ST_B(0, 5, 0);
  asm volatile("s_waitcnt vmcnt(0)" ::: "memory");
  __builtin_amdgcn_s_barrier();

#pragma unroll 1
  for (int t = 0; t < 16; ++t) {
    int b = t & 1;
    const u16* la = laR + b * 16384;
    const u16* lb = lbR + b * 24576;
    bool st = (t < 15);
    int kn = t + 1;

#pragma unroll
    for (int q = 0; q < 2; ++q) {
      bf16x8 af[4][2];
      // af reads for this Q-half (8 x b128), issued in the ni=0 phase
#pragma unroll
      for (int mi = 0; mi < 4; ++mi) {
        af[mi][0] = *(const bf16x8*)(la + (q * 64 + mi * 16) * 64 + ck0);
        af[mi][1] = *(const bf16x8*)(la + (q * 64 + mi * 16) * 64 + ck1);
      }
#pragma unroll
      for (int ni = 0; ni < 6; ++ni) {
        bf16x8 bfr0 = *(const bf16x8*)(lb + ni * 1024 + ck0);
        bf16x8 bfr1 = *(const bf16x8*)(lb + ni * 1024 + ck1);
        // staging: A passes at (q0, ni1..4); B passes at (q0,ni5) + (q1,ni0..4)
        if (st) {
          if (q == 0 && ni >= 1 && ni <= 4) { ST_A(b ^ 1, ni - 1, kn); }
          else if (q == 0 && ni == 5)       { ST_B(b ^ 1, 0, kn); }
          else if (q == 1 && ni <= 4)       { ST_B(b ^ 1, ni + 1, kn); }
        }
        SBAR();
        LGKM0();
        __builtin_amdgcn_s_setprio(1);
#pragma unroll
        for (int mi = 0; mi < 4; ++mi) {
          acc[q * 4 + mi][ni] = MFMA_(af[mi][0], bfr0, acc[q * 4 + mi][ni]);
          acc[q * 4 + mi][ni] = MFMA_(af[mi][1], bfr1, acc[q * 4 + mi][ni]);
        }
        __builtin_amdgcn_s_setprio(0);
        if (q == 1 && ni == 5) {
          if (st) { asm volatile("s_waitcnt vmcnt(0)" ::: "memory"); }  // ~full-tile cover
        }
        SBAR();
      }
    }
  }
#undef ST_A
#undef ST_B
#undef SBAR
#undef LGKM0
#undef MFMA_

  // ---- epilogue: inline bias, bf16, scatter q/k [b,h,n,d]; V direct-transposed [b,h,d,n] ----
#pragma unroll
  for (int ni = 0; ni < 6; ++ni) {
    int c = n0 + wn * 96 + ni * 16 + lo;   // 0..3071; 16-col groups never straddle q/k/v
    float bvl = (c < 1024) ? bq[c] * QSCALE : bkv[c - 1024];
    if (c < 2048) {
#pragma unroll
      for (int mi = 0; mi < 8; ++mi) {
#pragma unroll
        for (int r = 0; r < 4; ++r) {
          int m = m0 + wm * 128 + mi * 16 + hi * 4 + r;
          int b = m >> 10, tok = m & 1023;
          u16 o = f2bf(acc[mi][ni][r] + bvl);
          if (c < 1024) {
            int h = c >> 6, d = c & 63;
            qws[((size_t)(b * 16 + h) * 1024 + tok) * 64 + d] = o;
          } else {
            int c2 = c - 1024; int h = c2 >> 6, d = c2 & 63;
            kws[((size_t)(b * 16 + h) * 1024 + tok) * 64 + d] = o;
          }
        }
      }
    } else {
      int c2 = c - 2048; int h = c2 >> 6, d = c2 & 63;
#pragma unroll
      for (int mi = 0; mi < 8; ++mi) {
        int m = m0 + wm * 128 + mi * 16 + hi * 4;   // 4-aligned, never crosses batch
        int b = m >> 10, tok = m & 1023;
        ushort4 pk;
        pk.x = bfc(acc[mi][ni][0] + bvl);
        pk.y = bfc(acc[mi][ni][1] + bvl);
        pk.z = bfc(acc[mi][ni][2] + bvl);
        pk.w = bfc(acc[mi][ni][3] + bvl);
        *(ushort4*)&vtw[((size_t)(b * 16 + h) * 64 + d) * 1024 + tok] = pk;
      }
    }
  }
}

// ---------------- flash attention: 2 q-sets per block ----------------
// grid (bh=128, qb=4): each block processes q0 and q0+128 against the SAME
// staged K/V tiles; K/V fragments read from LDS once, used for both q-sets.
// Swapped QK^T + in-lane softmax + defer-max (THR=8, log2 domain); T5 setprio.
__launch_bounds__(512)
__global__ void k_attn(const u16* __restrict__ q, const u16* __restrict__ k,
                       const u16* __restrict__ vt, float* __restrict__ out) {
  __shared__ __align__(16) u16 Ks[2][4096];    // [buf][row*64+col], chunk-swizzled
  __shared__ __align__(16) u16 Vs[2][4096];    // [buf][d*64+k], chunk-swizzled
  __shared__ __align__(16) u16 P[2][8][16][72]; // per-qset, per-wave P relayout [q][key]
  int bh = blockIdx.x;
  int q0 = blockIdx.y * 256;
  int tid = threadIdx.x;
  int w = tid >> 6, lane = tid & 63;
  int lo = lane & 15, hi = lane >> 4;
  int b = bh >> 4, h = bh & 15;

  const u16* kbase = k  + (size_t)bh * 65536;
  const u16* vbase = vt + (size_t)bh * 65536;

  int srow = w * 8 + (lane >> 3);
  int cg   = (lane & 7) ^ ((lane >> 3) & 7);
  const u16* gK = kbase + (size_t)srow * 64   + cg * 8;
  const u16* gV = vbase + (size_t)srow * 1024 + cg * 8;
  u16* lK0 = &Ks[0][w * 512];
  u16* lK1 = &Ks[1][w * 512];
  u16* lV0 = &Vs[0][w * 512];
  u16* lV1 = &Vs[1][w * 512];

  const u16* qp = q + ((size_t)bh * 1024 + q0 + w * 16 + lo) * 64 + hi * 8;
  bf16x8 qfA0 = *(const bf16x8*)(qp);
  bf16x8 qfA1 = *(const bf16x8*)(qp + 32);
  bf16x8 qfB0 = *(const bf16x8*)(qp + 128 * 64);
  bf16x8 qfB1 = *(const bf16x8*)(qp + 128 * 64 + 32);

  f32x4 accA[4] = {}, accB[4] = {};
  float mA = -1e30f, lA = 0.f;
  float mB = -1e30f, lB = 0.f;

  int sw = lo & 7;

  gload16(gK, lK0);
  gload16(gV, lV0);
  __syncthreads();

  for (int t = 0; t < 16; ++t) {
    int cur = t & 1;
    if (t < 15) {
      gload16(gK + (t + 1) * 4096, cur ? lK0 : lK1);
      gload16(gV + (t + 1) * 64,   cur ? lV0 : lV1);
    }
    // ---- S^T for both q-sets; K frags read ONCE ----
    f32x4 sA[4] = {}, sB[4] = {};
    const u16* kb = Ks[cur];
    __builtin_amdgcn_s_setprio(1);
#pragma unroll
    for (int ni = 0; ni < 4; ++ni) {
      const u16* kp = kb + (ni * 16 + lo) * 64;
      bf16x8 kf0 = *(const bf16x8*)(kp + ((hi ^ sw) * 8));
      bf16x8 kf1 = *(const bf16x8*)(kp + (((4 + hi) ^ sw) * 8));
      sA[ni] = __builtin_amdgcn_mfma_f32_16x16x32_bf16(kf0, qfA0, sA[ni], 0, 0, 0);
      sA[ni] = __builtin_amdgcn_mfma_f32_16x16x32_bf16(kf1, qfA1, sA[ni], 0, 0, 0);
      sB[ni] = __builtin_amdgcn_mfma_f32_16x16x32_bf16(kf0, qfB0, sB[ni], 0, 0, 0);
      sB[ni] = __builtin_amdgcn_mfma_f32_16x16x32_bf16(kf1, qfB1, sB[ni], 0, 0, 0);
    }
    __builtin_amdgcn_s_setprio(0);

    // ---- softmax A and B (independent VALU chains) ----
#define SOFTMAX(S, M, L, PI)                                                   \
    {                                                                          \
      float a0 = fmaxf(fmaxf(S[0][0], S[0][1]), fmaxf(S[0][2], S[0][3]));      \
      float a1 = fmaxf(fmaxf(S[1][0], S[1][1]), fmaxf(S[1][2], S[1][3]));      \
      float a2 = fmaxf(fmaxf(S[2][0], S[2][1]), fmaxf(S[2][2], S[2][3]));      \
      float a3 = fmaxf(fmaxf(S[3][0], S[3][1]), fmaxf(S[3][2], S[3][3]));      \
      float pm = fmaxf(fmaxf(a0, a1), fmaxf(a2, a3));                          \
      pm = fmaxf(pm, __shfl_xor(pm, 16));                                      \
      pm = fmaxf(pm, __shfl_xor(pm, 32));                                      \
      if (!__all(pm <= M + 8.0f)) {                                            \
        float mn = fmaxf(M, pm);                                               \
        float corr = __builtin_amdgcn_exp2f(M - mn);                           \
        M = mn;                                                                \
        L *= corr;                                                             \
        float cr[4];                                                           \
        _Pragma("unroll")                                                      \
        for (int r = 0; r < 4; ++r) cr[r] = __shfl(corr, hi * 4 + r);          \
        _Pragma("unroll")                                                      \
        for (int ci = 0; ci < 4; ++ci)                                         \
          _Pragma("unroll")                                                    \
          for (int r = 0; r < 4; ++r) acc##PI[ci][r] *= cr[r];                 \
      }                                                                        \
      float rs = 0.f;                                                          \
      _Pragma("unroll")                                                        \
      for (int ni = 0; ni < 4; ++ni) {                                         \
        float p0 = __builtin_amdgcn_exp2f(S[ni][0] - M);                       \
        float p1 = __builtin_amdgcn_exp2f(S[ni][1] - M);                       \
        float p2 = __builtin_amdgcn_exp2f(S[ni][2] - M);                       \
        float p3 = __builtin_amdgcn_exp2f(S[ni][3] - M);                       \
        rs += (p0 + p1) + (p2 + p3);                                           \
        ushort4 pk;                                                            \
        pk.x = bfc(p0); pk.y = bfc(p1); pk.z = bfc(p2); pk.w = bfc(p3);        \
        *(ushort4*)&P[PI##I][w][lo][ni * 16 + hi * 4] = pk;                    \
      }                                                                        \
      rs += __shfl_xor(rs, 16);                                                \
      rs += __shfl_xor(rs, 32);                                                \
      L += rs;                                                                 \
    }
#define AI 0
#define BI 1
    SOFTMAX(sA, mA, lA, A)
    SOFTMAX(sB, mB, lB, B)
#undef SOFTMAX

    // ---- PV for both q-sets; V frags read ONCE ----
    bf16x8 pA0 = *(const bf16x8*)(&P[0][w][lo][hi * 8]);
    bf16x8 pA1 = *(const bf16x8*)(&P[0][w][lo][32 + hi * 8]);
    bf16x8 pB0 = *(const bf16x8*)(&P[1][w][lo][hi * 8]);
    bf16x8 pB1 = *(const bf16x8*)(&P[1][w][lo][32 + hi * 8]);
    const u16* vb = Vs[cur];
    __builtin_amdgcn_s_setprio(1);
#pragma unroll
    for (int ci = 0; ci < 4; ++ci) {
      const u16* vp = vb + (ci * 16 + lo) * 64;
      bf16x8 vf0 = *(const bf16x8*)(vp + ((hi ^ sw) * 8));
      bf16x8 vf1 = *(const bf16x8*)(vp + (((4 + hi) ^ sw) * 8));
      accA[ci] = __builtin_amdgcn_mfma_f32_16x16x32_bf16(pA0, vf0, accA[ci], 0, 0, 0);
      accA[ci] = __builtin_amdgcn_mfma_f32_16x16x32_bf16(pA1, vf1, accA[ci], 0, 0, 0);
      accB[ci] = __builtin_amdgcn_mfma_f32_16x16x32_bf16(pB0, vf0, accB[ci], 0, 0, 0);
      accB[ci] = __builtin_amdgcn_mfma_f32_16x16x32_bf16(pB1, vf1, accB[ci], 0, 0, 0);
    }
    __builtin_amdgcn_s_setprio(0);
    __syncthreads();
  }
  // ---- normalize + store both q-sets ----
  {
    float inv = 1.0f / lA;
    float ivr[4];
#pragma unroll
    for (int r = 0; r < 4; ++r) ivr[r] = __shfl(inv, hi * 4 + r);
#pragma unroll
    for (int r = 0; r < 4; ++r) {
      int n = q0 + w * 16 + hi * 4 + r;
      float* dst = out + ((size_t)(b * 1024 + n)) * 1024 + h * 64;
#pragma unroll
      for (int ci = 0; ci < 4; ++ci) dst[ci * 16 + lo] = accA[ci][r] * ivr[r];
    }
  }
  {
    float inv = 1.0f / lB;
    float ivr[4];
#pragma unroll
    for (int r = 0; r < 4; ++r) ivr[r] = __shfl(inv, hi * 4 + r);
#pragma unroll
    for (int r = 0; r < 4; ++r) {
      int n = q0 + 128 + w * 16 + hi * 4 + r;
      float* dst = out + ((size_t)(b * 1024 + n)) * 1024 + h * 64;
#pragma unroll
      for (int ci = 0; ci < 4; ++ci) dst[ci * 16 + lo] = accB[ci][r] * ivr[r];
    }
  }
}

extern "C" void kernel_launch(void* const* d_in, const int* in_sizes, int n_in,
                              void* d_out, int out_size, void* d_ws, size_t ws_size,
                              hipStream_t stream) {
  const float* x   = (const float*)d_in[0];
  const float* Wq  = (const float*)d_in[1];
  const float* bq  = (const float*)d_in[2];
  const float* Wkv = (const float*)d_in[3];
  const float* bkv = (const float*)d_in[4];
  float* out = (float*)d_out;

  char* ws = (char*)d_ws;
  u16*   xb   = (u16*)(ws);                       // 16,777,216 B
  u16*   Wt   = (u16*)(ws + 16777216);            //  6,291,456 B
  u16*   qws  = (u16*)(ws + 23080960);            // 16,777,216 B
  u16*   kws  = (u16*)(ws + 39858176);            // 16,777,216 B
  u16*   vtw  = (u16*)(ws + 73412608);            // 16,777,216 B (written transposed by k_gemm)

  k_prep<<<8960, 256, 0, stream>>>(x, Wq, Wkv, xb, Wt);
  k_gemm<<<256, 512, 0, stream>>>(xb, Wt, bq, bkv, qws, kws, vtw);
  {
    dim3 g(128, 4);
    k_attn<<<g, 512, 0, stream>>>(qws, kws, vtw, out);
  }
}